// Round 10
// baseline (176.719 us; speedup 1.0000x reference)
//
#include <hip/hip_runtime.h>
#include <hip/hip_bf16.h>
#include <math.h>

using bf16 = __hip_bfloat16;
typedef __attribute__((ext_vector_type(8))) short bf16x8;
typedef __attribute__((ext_vector_type(4))) short bf16x4;
typedef __attribute__((ext_vector_type(4))) float f32x4;
typedef __attribute__((ext_vector_type(2))) int i32x2;

// async global->LDS, 16B per lane (guide §5: width=16 is the m93->m97 2x step)
static __device__ __forceinline__ void gl_lds16(const void* g, void* l) {
  __builtin_amdgcn_global_load_lds(
      (const __attribute__((address_space(1))) unsigned int*)g,
      (__attribute__((address_space(3))) unsigned int*)l, 16, 0, 0);
}

#define MFMA16 __builtin_amdgcn_mfma_f32_16x16x32_bf16
#define MFMA16K16 __builtin_amdgcn_mfma_f32_16x16x16bf16_1k

// fast f32->bf16 (round-to-nearest-ish; fine for p in [0,1] and O outputs)
static __device__ __forceinline__ short f2bf(float f) {
  return (short)((__builtin_bit_cast(unsigned int, f) + 0x8000u) >> 16);
}

// ---------------------------------------------------------------------------
// Kernel 0: fp32 -> bf16 for all three inputs in ONE launch.
// grid 8192: [0,4096) x, [4096,7168) Wqkv, [7168,8192) Wout.
// ---------------------------------------------------------------------------
__global__ __launch_bounds__(256) void cvt_all(
    const float* __restrict__ x, const float* __restrict__ wqkv,
    const float* __restrict__ wout, bf16* __restrict__ xb,
    bf16* __restrict__ wqkvb, bf16* __restrict__ woutb) {
  const int blk = blockIdx.x;
  const float* src;
  bf16* dst;
  int base;
  if (blk < 4096) {
    src = x; dst = xb; base = blk;
  } else if (blk < 7168) {
    src = wqkv; dst = wqkvb; base = blk - 4096;
  } else {
    src = wout; dst = woutb; base = blk - 7168;
  }
  const int i = (base * 256 + threadIdx.x) * 4;
  const float4 v = *(const float4*)(src + i);
  bf16x4 o;
  o.x = f2bf(v.x);
  o.y = f2bf(v.y);
  o.z = f2bf(v.z);
  o.w = f2bf(v.w);
  *(bf16x4*)(dst + i) = o;
}

// ---------------------------------------------------------------------------
// 128x128 block of C[m,n] = sum_k A[m,k]*B[n,k]   (A:[*,K] row-major, B:[*,K])
// ---------------------------------------------------------------------------
template <int K>
static __device__ __forceinline__ void gemm_bt_acc(
    const bf16* __restrict__ A, const bf16* __restrict__ B,
    int rowA0, int rowB0, bf16* As, bf16* Bs, f32x4 acc[4][4]) {
  const int t = threadIdx.x;
  const int w = t >> 6, l = t & 63;
  const int quad = l >> 4, l16 = l & 15;
  const int wm = (w >> 1) * 64, wn = (w & 1) * 64;
  const int c0 = t, c1 = t + 256;
  const bf16* a0 = A + (size_t)(rowA0 + (c0 >> 2)) * K + (c0 & 3) * 8;
  const bf16* a1 = A + (size_t)(rowA0 + (c1 >> 2)) * K + (c1 & 3) * 8;
  const bf16* b0 = B + (size_t)(rowB0 + (c0 >> 2)) * K + (c0 & 3) * 8;
  const bf16* b1 = B + (size_t)(rowB0 + (c1 >> 2)) * K + (c1 & 3) * 8;
  for (int k0 = 0; k0 < K; k0 += 32) {
    __syncthreads();
    gl_lds16(a0 + k0, As + c0 * 8);
    gl_lds16(a1 + k0, As + c1 * 8);
    gl_lds16(b0 + k0, Bs + c0 * 8);
    gl_lds16(b1 + k0, Bs + c1 * 8);
    __syncthreads();
    bf16x8 af[4], bg[4];
#pragma unroll
    for (int i = 0; i < 4; i++)
      af[i] = *(const bf16x8*)(As + (wm + i * 16 + l16) * 32 + quad * 8);
#pragma unroll
    for (int j = 0; j < 4; j++)
      bg[j] = *(const bf16x8*)(Bs + (wn + j * 16 + l16) * 32 + quad * 8);
#pragma unroll
    for (int i = 0; i < 4; i++)
#pragma unroll
      for (int j = 0; j < 4; j++)
        acc[i][j] = MFMA16(af[i], bg[j], acc[i][j], 0, 0, 0);
  }
}

// ---------------------------------------------------------------------------
// Kernel 1: qkv = x @ Wqkv^T ; scatter Q*0.125 (pre-scaled), K, Vt.
// V stores vectorized (r indexes contiguous s in Vt[bh][d][s]).
// ---------------------------------------------------------------------------
__global__ __launch_bounds__(256) void qkv_gemm(
    const bf16* __restrict__ x, const bf16* __restrict__ Wqkv,
    bf16* __restrict__ Qb, bf16* __restrict__ Kb, bf16* __restrict__ Vt) {
  __shared__ bf16 As[128 * 32];
  __shared__ bf16 Bs[128 * 32];
  f32x4 acc[4][4];
#pragma unroll
  for (int i = 0; i < 4; i++)
#pragma unroll
    for (int j = 0; j < 4; j++) acc[i][j] = (f32x4){0.f, 0.f, 0.f, 0.f};
  const int bm = blockIdx.x, bn = blockIdx.y;
  gemm_bt_acc<1024>(x, Wqkv, bm * 128, bn * 128, As, Bs, acc);

  const int t = threadIdx.x, w = t >> 6, l = t & 63;
  const int quad = l >> 4, l16 = l & 15;
  const int wm = (w >> 1) * 64, wn = (w & 1) * 64;
#pragma unroll
  for (int i = 0; i < 4; i++) {
    const int m0 = bm * 128 + wm + i * 16 + quad * 4;  // 4 contiguous m (=s)
    const int b = m0 >> 11, s0 = m0 & 2047;            // same b for all 4 r
#pragma unroll
    for (int j = 0; j < 4; j++) {
      const int n = bn * 128 + wn + j * 16 + l16;  // 0..3071
      const int which = n >> 10;
      const int nn = n & 1023;
      const int h = nn >> 6, d = nn & 63;
      const int bh = b * 16 + h;
      if (which == 2) {  // V: contiguous s -> one vectorized store
        bf16x4 v4;
#pragma unroll
        for (int r = 0; r < 4; r++)
          v4[r] = (short)__builtin_bit_cast(unsigned short,
                                            __float2bfloat16(acc[i][j][r]));
        *(bf16x4*)(Vt + ((size_t)bh * 64 + d) * 2048 + s0) = v4;
      } else {
        const float sc = (which == 0) ? 0.125f : 1.0f;  // fold softmax scale
        bf16* dst = (which == 0) ? Qb : Kb;
#pragma unroll
        for (int r = 0; r < 4; r++)
          dst[((size_t)bh * 2048 + s0 + r) * 64 + d] =
              __float2bfloat16(acc[i][j][r] * sc);
      }
    }
  }
}

// ---------------------------------------------------------------------------
// Kernel 2: causal flash attention. Register-resident P; 128-row Q-tiles
// (4 waves x 32 q: halves per-q LDS read redundancy vs 16 q/wave — each
// wave's full K/V tile re-read now serves 2x the q rows), 128-wide K-tiles,
// Q pre-scaled. Denominator via ones-row MFMA. P packed with v_perm.
// grid(512): bh=x&31, idx=x>>5 in 0..15, qt = idx<8 ? idx : 23-idx
// (co-resident block pairs on a CU sum to njj 17 -> balanced LDS demand).
// LDS 48K (Qs16+Ks16+Vts16) -> 2 blocks/CU by grid.
// ---------------------------------------------------------------------------
__global__ __launch_bounds__(256) void attn_kernel(
    const bf16* __restrict__ Qb, const bf16* __restrict__ Kb,
    const bf16* __restrict__ Vt, bf16* __restrict__ attn) {
  __shared__ bf16 Qs[128 * 64];   // [qrow][d]  swizzled (8 chunks/row)
  __shared__ bf16 Ks[128 * 64];   // [krow][d]  swizzled (8 chunks/row)
  __shared__ bf16 Vts[64 * 128];  // [d][s]     swizzled (16 chunks/row)
  const int x = blockIdx.x;
  const int bh = x & 31;
  const int idx = x >> 5;                     // 0..15
  const int qt = (idx < 8) ? idx : 23 - idx;  // CU-pairs sum to 15 -> balance
  const int q0 = qt * 128;
  const int t = threadIdx.x, w = t >> 6, l = t & 63;
  const int quad = l >> 4, l16 = l & 15;
  const bf16x4 ones = {16256, 16256, 16256, 16256};  // bf16 1.0 x4
  const int b = bh >> 4, h = bh & 15;

  // ---- stage Q (swizzled source permutation; LDS dest lane-linear) ----
  const bf16* Qg = Qb + ((size_t)bh * 2048 + q0) * 64;
#pragma unroll
  for (int c = t; c < 1024; c += 256) {
    const int row = c >> 3, pos = c & 7;
    gl_lds16(Qg + (row * 8 + (pos ^ (row & 7))) * 8, Qs + c * 8);
  }

  f32x4 oacc[2][4];  // [nt][md d-16]; O^T: q=l16, d=quad*4+reg
  f32x4 lacc[2];     // ones·P = denominator (q=l16), per nt
#pragma unroll
  for (int nt = 0; nt < 2; nt++) {
    lacc[nt] = (f32x4){0.f, 0.f, 0.f, 0.f};
#pragma unroll
    for (int md = 0; md < 4; md++) oacc[nt][md] = (f32x4){0.f, 0.f, 0.f, 0.f};
  }

  const int njj = qt + 1;  // 128-wide tiles covering cols 0..q0+127
  for (int jj = 0; jj < njj; jj++) {
    const int j0 = jj * 128;
    __syncthreads();  // prior iter's Ks/Vts reads complete
    const bf16* Kg = Kb + ((size_t)bh * 2048 + j0) * 64;
#pragma unroll
    for (int c = t; c < 1024; c += 256) {
      const int row = c >> 3, pos = c & 7;
      gl_lds16(Kg + (row * 8 + (pos ^ (row & 7))) * 8, Ks + c * 8);
    }
    const bf16* Vg = Vt + (size_t)bh * 64 * 2048 + j0;
#pragma unroll
    for (int c = t; c < 1024; c += 256) {
      const int d = c >> 4, pos = c & 15;
      gl_lds16(Vg + (size_t)d * 2048 + ((pos ^ (d & 15)) * 8), Vts + c * 8);
    }
    __syncthreads();  // staging visible (covers Qs on jj==0 too)

    // ---- S^T = K Q^T : A=K[s][d] (M=128), B=Q^T[d][q] (2x16 q of wave) ----
    f32x4 sacc[2][8];  // [nt][mt s-16];  C-layout: q=l16, s=quad*4+reg
#pragma unroll
    for (int nt = 0; nt < 2; nt++)
#pragma unroll
      for (int mt = 0; mt < 8; mt++) sacc[nt][mt] = (f32x4){0.f, 0.f, 0.f, 0.f};
#pragma unroll
    for (int kk = 0; kk < 2; kk++) {
      bf16x8 qf[2];
#pragma unroll
      for (int nt = 0; nt < 2; nt++) {
        const int qrow = w * 32 + nt * 16 + l16;
        const int qpos = (kk * 4 + quad) ^ (qrow & 7);
        qf[nt] = *(const bf16x8*)(Qs + qrow * 64 + qpos * 8);
      }
#pragma unroll
      for (int mt = 0; mt < 8; mt++) {
        const int row = mt * 16 + l16;
        const int pos = (kk * 4 + quad) ^ (row & 7);
        bf16x8 kf = *(const bf16x8*)(Ks + row * 64 + pos * 8);
#pragma unroll
        for (int nt = 0; nt < 2; nt++)
          sacc[nt][mt] = MFMA16(kf, qf[nt], sacc[nt][mt], 0, 0, 0);
      }
    }

    // ---- P^T = exp(S^T) packed via v_perm (B-frag layout) ----
    bf16x4 pfrag[2][8];   // [nt][kt = s-16-block]
    if (jj == njj - 1) {  // wave-uniform: only the last tile masks
#pragma unroll
      for (int nt = 0; nt < 2; nt++) {
        const int qi = q0 + w * 32 + nt * 16 + l16;
#pragma unroll
        for (int mt = 0; mt < 8; mt++) {
          unsigned rb[4];
#pragma unroll
          for (int r = 0; r < 4; r++) {
            const int sg = j0 + mt * 16 + quad * 4 + r;
            const float p = (sg <= qi) ? __expf(sacc[nt][mt][r]) : 0.f;
            rb[r] = __builtin_bit_cast(unsigned, p) + 0x8000u;
          }
          i32x2 pk;
          pk.x = (int)__builtin_amdgcn_perm(rb[1], rb[0], 0x07060302u);
          pk.y = (int)__builtin_amdgcn_perm(rb[3], rb[2], 0x07060302u);
          pfrag[nt][mt] = __builtin_bit_cast(bf16x4, pk);
        }
      }
    } else {
#pragma unroll
      for (int nt = 0; nt < 2; nt++) {
#pragma unroll
        for (int mt = 0; mt < 8; mt++) {
          unsigned rb[4];
#pragma unroll
          for (int r = 0; r < 4; r++) {
            const float p = __expf(sacc[nt][mt][r]);
            rb[r] = __builtin_bit_cast(unsigned, p) + 0x8000u;
          }
          i32x2 pk;
          pk.x = (int)__builtin_amdgcn_perm(rb[1], rb[0], 0x07060302u);
          pk.y = (int)__builtin_amdgcn_perm(rb[3], rb[2], 0x07060302u);
          pfrag[nt][mt] = __builtin_bit_cast(bf16x4, pk);
        }
      }
    }

    // ---- O^T += V^T P^T ; lacc += ones·P^T. V fragment read once per
    // (kt,md), reused for both nt -> per-q V LDS traffic halved. ----
#pragma unroll
    for (int kt = 0; kt < 8; kt++) {
#pragma unroll
      for (int nt = 0; nt < 2; nt++)
        lacc[nt] = MFMA16K16(ones, pfrag[nt][kt], lacc[nt], 0, 0, 0);
#pragma unroll
      for (int md = 0; md < 4; md++) {
        const int d = md * 16 + l16;
        const int pos = (kt * 2 + (quad >> 1)) ^ (d & 15);
        bf16x4 va = *(const bf16x4*)(Vts + d * 128 + pos * 8 + (quad & 1) * 4);
#pragma unroll
        for (int nt = 0; nt < 2; nt++)
          oacc[nt][md] = MFMA16K16(va, pfrag[nt][kt], oacc[nt][md], 0, 0, 0);
      }
    }
  }

  // ---- epilogue: every lane holds its q's full denominator ----
#pragma unroll
  for (int nt = 0; nt < 2; nt++) {
    const float inv = 1.0f / lacc[nt][0];
    const int srow = q0 + w * 32 + nt * 16 + l16;
#pragma unroll
    for (int md = 0; md < 4; md++) {
      bf16x4 o4;
#pragma unroll
      for (int r = 0; r < 4; r++) o4[r] = f2bf(oacc[nt][md][r] * inv);
      *(bf16x4*)(attn + ((size_t)b * 2048 + srow) * 1024 + h * 64 + md * 16 +
                 quad * 4) = o4;
    }
  }
}

// ---------------------------------------------------------------------------
// Kernel 3: out = attn @ Wout^T (fp32 output). 128x64 tiles -> grid (32,16)
// = 512 blocks = 2/CU.
// ---------------------------------------------------------------------------
__global__ __launch_bounds__(256) void out_gemm(
    const bf16* __restrict__ attn, const bf16* __restrict__ Wout,
    float* __restrict__ out) {
  __shared__ bf16 As[128 * 32];
  __shared__ bf16 Bs[64 * 32];
  f32x4 acc[4][2];
#pragma unroll
  for (int i = 0; i < 4; i++)
#pragma unroll
    for (int j = 0; j < 2; j++) acc[i][j] = (f32x4){0.f, 0.f, 0.f, 0.f};
  const int bm = blockIdx.x, bn = blockIdx.y;
  const int t = threadIdx.x, w = t >> 6, l = t & 63;
  const int quad = l >> 4, l16 = l & 15;
  const int wm = (w >> 1) * 64, wn = (w & 1) * 32;
  const int c0 = t, c1 = t + 256;
  const bf16* a0 = attn + (size_t)(bm * 128 + (c0 >> 2)) * 1024 + (c0 & 3) * 8;
  const bf16* a1 = attn + (size_t)(bm * 128 + (c1 >> 2)) * 1024 + (c1 & 3) * 8;
  const bf16* b0 = Wout + (size_t)(bn * 64 + (t >> 2)) * 1024 + (t & 3) * 8;
  for (int k0 = 0; k0 < 1024; k0 += 32) {
    __syncthreads();
    gl_lds16(a0 + k0, As + c0 * 8);
    gl_lds16(a1 + k0, As + c1 * 8);
    gl_lds16(b0 + k0, Bs + t * 8);
    __syncthreads();
    bf16x8 af[4], bg[2];
#pragma unroll
    for (int i = 0; i < 4; i++)
      af[i] = *(const bf16x8*)(As + (wm + i * 16 + l16) * 32 + quad * 8);
#pragma unroll
    for (int j = 0; j < 2; j++)
      bg[j] = *(const bf16x8*)(Bs + (wn + j * 16 + l16) * 32 + quad * 8);
#pragma unroll
    for (int i = 0; i < 4; i++)
#pragma unroll
      for (int j = 0; j < 2; j++)
        acc[i][j] = MFMA16(af[i], bg[j], acc[i][j], 0, 0, 0);
  }
#pragma unroll
  for (int i = 0; i < 4; i++) {
#pragma unroll
    for (int j = 0; j < 2; j++) {
      const int n = bn * 64 + wn + j * 16 + l16;
#pragma unroll
      for (int r = 0; r < 4; r++) {
        const int m = bm * 128 + wm + i * 16 + quad * 4 + r;
        out[(size_t)m * 1024 + n] = acc[i][j][r];
      }
    }
  }
}

// ---------------------------------------------------------------------------
extern "C" void kernel_launch(void* const* d_in, const int* in_sizes, int n_in,
                              void* d_out, int out_size, void* d_ws, size_t ws_size,
                              hipStream_t stream) {
  const float* x = (const float*)d_in[0];      // [2,2048,1024] fp32
  const float* Wqkv = (const float*)d_in[1];   // [3072,1024]   fp32
  const float* Wout = (const float*)d_in[2];   // [1024,1024]   fp32
  float* out = (float*)d_out;                  // [2,2048,1024] fp32

  char* ws = (char*)d_ws;
  const size_t MB = 1024 * 1024;
  bf16* xb = (bf16*)(ws + 0 * MB);      // [4096][1024]  8 MB (consumed by qkv)
  bf16* at = (bf16*)(ws + 0 * MB);      // [4096][1024]  8 MB (alias, after qkv)
  bf16* Wqkvb = (bf16*)(ws + 8 * MB);   // [3072][1024]  6 MB
  bf16* Woutb = (bf16*)(ws + 14 * MB);  // [1024][1024]  2 MB
  bf16* Qb = (bf16*)(ws + 16 * MB);     // [32][2048][64] 8 MB (pre-scaled)
  bf16* Kb = (bf16*)(ws + 24 * MB);     // [32][2048][64] 8 MB
  bf16* Vt = (bf16*)(ws + 32 * MB);     // [32][64][2048] 8 MB

  cvt_all<<<8192, 256, 0, stream>>>(x, Wqkv, Wout, xb, Wqkvb, Woutb);
  qkv_gemm<<<dim3(32, 24), 256, 0, stream>>>(xb, Wqkvb, Qb, Kb, Vt);
  attn_kernel<<<512, 256, 0, stream>>>(Qb, Kb, Vt, at);
  out_gemm<<<dim3(32, 16), 256, 0, stream>>>(at, Woutb, out);
}

// Round 11
// 169.710 us; speedup vs baseline: 1.0413x; 1.0413x over previous
//
#include <hip/hip_runtime.h>
#include <hip/hip_bf16.h>
#include <math.h>

using bf16 = __hip_bfloat16;
typedef __attribute__((ext_vector_type(8))) short bf16x8;
typedef __attribute__((ext_vector_type(4))) short bf16x4;
typedef __attribute__((ext_vector_type(4))) float f32x4;
typedef __attribute__((ext_vector_type(2))) int i32x2;

// async global->LDS, 16B per lane (guide §5: width=16 is the m93->m97 2x step)
static __device__ __forceinline__ void gl_lds16(const void* g, void* l) {
  __builtin_amdgcn_global_load_lds(
      (const __attribute__((address_space(1))) unsigned int*)g,
      (__attribute__((address_space(3))) unsigned int*)l, 16, 0, 0);
}

#define MFMA16 __builtin_amdgcn_mfma_f32_16x16x32_bf16
#define MFMA16K16 __builtin_amdgcn_mfma_f32_16x16x16bf16_1k

// fast f32->bf16 (round-to-nearest-ish; error margin is wide: 0.0156 vs 0.0766)
static __device__ __forceinline__ short f2bf(float f) {
  return (short)((__builtin_bit_cast(unsigned int, f) + 0x8000u) >> 16);
}

// ---------------------------------------------------------------------------
// Kernel 0: fp32 -> bf16 for all three inputs in ONE launch.
// grid 8192: [0,4096) x, [4096,7168) Wqkv, [7168,8192) Wout.
// ---------------------------------------------------------------------------
__global__ __launch_bounds__(256) void cvt_all(
    const float* __restrict__ x, const float* __restrict__ wqkv,
    const float* __restrict__ wout, bf16* __restrict__ xb,
    bf16* __restrict__ wqkvb, bf16* __restrict__ woutb) {
  const int blk = blockIdx.x;
  const float* src;
  bf16* dst;
  int base;
  if (blk < 4096) {
    src = x; dst = xb; base = blk;
  } else if (blk < 7168) {
    src = wqkv; dst = wqkvb; base = blk - 4096;
  } else {
    src = wout; dst = woutb; base = blk - 7168;
  }
  const int i = (base * 256 + threadIdx.x) * 4;
  const float4 v = *(const float4*)(src + i);
  bf16x4 o;
  o.x = f2bf(v.x);
  o.y = f2bf(v.y);
  o.z = f2bf(v.z);
  o.w = f2bf(v.w);
  *(bf16x4*)(dst + i) = o;
}

// ---------------------------------------------------------------------------
// 128x128 block of C = A·B^T (TRANS=false) or its transpose (TRANS=true,
// MFMA operands swapped: m lands on l16, n on quad*4+reg -> vectorizable
// n-contiguous epilogue stores).  A:[*,K] row-major, B:[*,K] row-major.
// ---------------------------------------------------------------------------
template <int K, bool TRANS>
static __device__ __forceinline__ void gemm_bt_acc(
    const bf16* __restrict__ A, const bf16* __restrict__ B,
    int rowA0, int rowB0, bf16* As, bf16* Bs, f32x4 acc[4][4]) {
  const int t = threadIdx.x;
  const int w = t >> 6, l = t & 63;
  const int quad = l >> 4, l16 = l & 15;
  const int wm = (w >> 1) * 64, wn = (w & 1) * 64;
  const int c0 = t, c1 = t + 256;
  const bf16* a0 = A + (size_t)(rowA0 + (c0 >> 2)) * K + (c0 & 3) * 8;
  const bf16* a1 = A + (size_t)(rowA0 + (c1 >> 2)) * K + (c1 & 3) * 8;
  const bf16* b0 = B + (size_t)(rowB0 + (c0 >> 2)) * K + (c0 & 3) * 8;
  const bf16* b1 = B + (size_t)(rowB0 + (c1 >> 2)) * K + (c1 & 3) * 8;
  for (int k0 = 0; k0 < K; k0 += 32) {
    __syncthreads();
    gl_lds16(a0 + k0, As + c0 * 8);
    gl_lds16(a1 + k0, As + c1 * 8);
    gl_lds16(b0 + k0, Bs + c0 * 8);
    gl_lds16(b1 + k0, Bs + c1 * 8);
    __syncthreads();
    bf16x8 af[4], bg[4];
#pragma unroll
    for (int i = 0; i < 4; i++)
      af[i] = *(const bf16x8*)(As + (wm + i * 16 + l16) * 32 + quad * 8);
#pragma unroll
    for (int j = 0; j < 4; j++)
      bg[j] = *(const bf16x8*)(Bs + (wn + j * 16 + l16) * 32 + quad * 8);
#pragma unroll
    for (int i = 0; i < 4; i++)
#pragma unroll
      for (int j = 0; j < 4; j++)
        acc[i][j] = TRANS ? MFMA16(bg[j], af[i], acc[i][j], 0, 0, 0)
                          : MFMA16(af[i], bg[j], acc[i][j], 0, 0, 0);
  }
}

// ---------------------------------------------------------------------------
// Kernel 1: qkv = x @ Wqkv^T ; scatter Q*0.125 (pre-scaled), K, Vt.
// `which` is block-uniform (bn<8 Q, <16 K, else V).  Q/K blocks compute the
// TRANSPOSED product so each lane holds 4 contiguous d -> one bf16x4 store
// per fragment (4x fewer store insts).  V blocks: normal orientation, r
// indexes contiguous s in Vt[bh][d][s] -> bf16x4 store.
// ---------------------------------------------------------------------------
__global__ __launch_bounds__(256) void qkv_gemm(
    const bf16* __restrict__ x, const bf16* __restrict__ Wqkv,
    bf16* __restrict__ Qb, bf16* __restrict__ Kb, bf16* __restrict__ Vt) {
  __shared__ bf16 As[128 * 32];
  __shared__ bf16 Bs[128 * 32];
  f32x4 acc[4][4];
#pragma unroll
  for (int i = 0; i < 4; i++)
#pragma unroll
    for (int j = 0; j < 4; j++) acc[i][j] = (f32x4){0.f, 0.f, 0.f, 0.f};
  const int bm = blockIdx.x, bn = blockIdx.y;
  const bool isV = (bn >= 16);
  if (isV)
    gemm_bt_acc<1024, false>(x, Wqkv, bm * 128, bn * 128, As, Bs, acc);
  else
    gemm_bt_acc<1024, true>(x, Wqkv, bm * 128, bn * 128, As, Bs, acc);

  const int t = threadIdx.x, w = t >> 6, l = t & 63;
  const int quad = l >> 4, l16 = l & 15;
  const int wm = (w >> 1) * 64, wn = (w & 1) * 64;
  if (isV) {
    // normal orientation: m = ...quad*4+r (contiguous s), n = ...l16 (d)
#pragma unroll
    for (int i = 0; i < 4; i++) {
      const int m0 = bm * 128 + wm + i * 16 + quad * 4;
      const int b = m0 >> 11, s0 = m0 & 2047;
#pragma unroll
      for (int j = 0; j < 4; j++) {
        const int nn = (bn * 128 + wn + j * 16 + l16) & 1023;
        const int h = nn >> 6, d = nn & 63;
        const int bh = b * 16 + h;
        bf16x4 v4;
#pragma unroll
        for (int r = 0; r < 4; r++) v4[r] = f2bf(acc[i][j][r]);
        *(bf16x4*)(Vt + ((size_t)bh * 64 + d) * 2048 + s0) = v4;
      }
    }
  } else {
    // transposed: m = ...l16 (s), n = ...quad*4+r (contiguous d)
    const float sc = (bn < 8) ? 0.125f : 1.0f;  // fold softmax scale into Q
    bf16* dst = (bn < 8) ? Qb : Kb;
#pragma unroll
    for (int i = 0; i < 4; i++) {
      const int m = bm * 128 + wm + i * 16 + l16;
      const int b = m >> 11, s = m & 2047;
#pragma unroll
      for (int j = 0; j < 4; j++) {
        const int nn = (bn * 128 + wn + j * 16 + quad * 4) & 1023;
        const int h = nn >> 6, d0 = nn & 63;
        const int bh = b * 16 + h;
        bf16x4 v4;
#pragma unroll
        for (int r = 0; r < 4; r++) v4[r] = f2bf(acc[i][j][r] * sc);
        *(bf16x4*)(dst + ((size_t)bh * 2048 + s) * 64 + d0) = v4;
      }
    }
  }
}

// ---------------------------------------------------------------------------
// Kernel 2: causal flash attention (R9's verified version). Register-resident
// P; 64-row Q-tiles, 128-wide K-tiles, Q pre-scaled. Denominator via ones-row
// MFMA. TWO diagonal-paired q-tiles per block (qt = idx and 31-idx): every
// block does 17-18 j-tiles -> per-BLOCK uniform work (R10 showed per-CU-pair
// balancing fails: short blocks exit and can't backfill).
// grid(512): bh = x&31, idx = x>>5 in 0..15. LDS 40K (Qs8+Ks16+Vts16).
// ---------------------------------------------------------------------------
__global__ __launch_bounds__(256) void attn_kernel(
    const bf16* __restrict__ Qb, const bf16* __restrict__ Kb,
    const bf16* __restrict__ Vt, bf16* __restrict__ attn) {
  __shared__ bf16 Qs[64 * 64];    // [qrow][d]  swizzled (8 chunks/row)
  __shared__ bf16 Ks[128 * 64];   // [krow][d]  swizzled (8 chunks/row)
  __shared__ bf16 Vts[64 * 128];  // [d][s]     swizzled (16 chunks/row)
  const int x = blockIdx.x;
  const int bh = x & 31;
  const int idx = x >> 5;  // 0..15
  const int t = threadIdx.x, w = t >> 6, l = t & 63;
  const int quad = l >> 4, l16 = l & 15;
  const bf16x4 ones = {16256, 16256, 16256, 16256};  // bf16 1.0 x4
  const int b = bh >> 4, h = bh & 15;

  for (int pass = 0; pass < 2; pass++) {
    const int qt = pass ? 31 - idx : idx;  // paired: total tiles 17-18
    const int q0 = qt * 64;
    if (pass) __syncthreads();  // pass-0 LDS reads complete before re-stage

    // ---- stage Q (swizzled source permutation; LDS dest lane-linear) ----
    const bf16* Qg = Qb + ((size_t)bh * 2048 + q0) * 64;
#pragma unroll
    for (int c = t; c < 512; c += 256) {
      const int row = c >> 3, pos = c & 7;
      gl_lds16(Qg + (row * 8 + (pos ^ (row & 7))) * 8, Qs + c * 8);
    }

    f32x4 oacc[4];  // [md d-16]; O^T: q=l16, d=quad*4+reg
    f32x4 lacc = (f32x4){0.f, 0.f, 0.f, 0.f};  // ones·P = denominator
#pragma unroll
    for (int md = 0; md < 4; md++) oacc[md] = (f32x4){0.f, 0.f, 0.f, 0.f};

    const int njj = (qt + 2) >> 1;  // 128-wide tiles covering cols 0..q0+63
    for (int jj = 0; jj < njj; jj++) {
      const int j0 = jj * 128;
      __syncthreads();  // prior iter's Ks/Vts reads complete
      const bf16* Kg = Kb + ((size_t)bh * 2048 + j0) * 64;
#pragma unroll
      for (int c = t; c < 1024; c += 256) {
        const int row = c >> 3, pos = c & 7;
        gl_lds16(Kg + (row * 8 + (pos ^ (row & 7))) * 8, Ks + c * 8);
      }
      const bf16* Vg = Vt + (size_t)bh * 64 * 2048 + j0;
#pragma unroll
      for (int c = t; c < 1024; c += 256) {
        const int d = c >> 4, pos = c & 15;
        gl_lds16(Vg + (size_t)d * 2048 + ((pos ^ (d & 15)) * 8), Vts + c * 8);
      }
      __syncthreads();  // staging visible (covers Qs on jj==0 too)

      // ---- S^T = K Q^T : A=K[s][d] (M=128), B=Q^T[d][q] (N=16 of wave) ----
      f32x4 sacc[8];  // [mt s-16];  C-layout: q=l16, s=quad*4+reg
#pragma unroll
      for (int mt = 0; mt < 8; mt++) sacc[mt] = (f32x4){0.f, 0.f, 0.f, 0.f};
#pragma unroll
      for (int kk = 0; kk < 2; kk++) {
        const int qrow = w * 16 + l16;
        const int qpos = (kk * 4 + quad) ^ (qrow & 7);
        bf16x8 qf = *(const bf16x8*)(Qs + qrow * 64 + qpos * 8);
#pragma unroll
        for (int mt = 0; mt < 8; mt++) {
          const int row = mt * 16 + l16;
          const int pos = (kk * 4 + quad) ^ (row & 7);
          bf16x8 kf = *(const bf16x8*)(Ks + row * 64 + pos * 8);
          sacc[mt] = MFMA16(kf, qf, sacc[mt], 0, 0, 0);
        }
      }

      // ---- P^T = exp(S^T) packed via v_perm (B-frag layout) ----
      bf16x4 pfrag[8];      // [kt = s-16-block]
      if (jj == njj - 1) {  // wave-uniform: only the last tile masks
        const int qi = q0 + w * 16 + l16;
#pragma unroll
        for (int mt = 0; mt < 8; mt++) {
          unsigned rb[4];
#pragma unroll
          for (int r = 0; r < 4; r++) {
            const int sg = j0 + mt * 16 + quad * 4 + r;
            const float p = (sg <= qi) ? __expf(sacc[mt][r]) : 0.f;
            rb[r] = __builtin_bit_cast(unsigned, p) + 0x8000u;
          }
          i32x2 pk;
          pk.x = (int)__builtin_amdgcn_perm(rb[1], rb[0], 0x07060302u);
          pk.y = (int)__builtin_amdgcn_perm(rb[3], rb[2], 0x07060302u);
          pfrag[mt] = __builtin_bit_cast(bf16x4, pk);
        }
      } else {
#pragma unroll
        for (int mt = 0; mt < 8; mt++) {
          unsigned rb[4];
#pragma unroll
          for (int r = 0; r < 4; r++) {
            const float p = __expf(sacc[mt][r]);
            rb[r] = __builtin_bit_cast(unsigned, p) + 0x8000u;
          }
          i32x2 pk;
          pk.x = (int)__builtin_amdgcn_perm(rb[1], rb[0], 0x07060302u);
          pk.y = (int)__builtin_amdgcn_perm(rb[3], rb[2], 0x07060302u);
          pfrag[mt] = __builtin_bit_cast(bf16x4, pk);
        }
      }

      // ---- O^T += V^T P^T ; lacc += ones·P^T (denominator in MFMA pipe) --
#pragma unroll
      for (int kt = 0; kt < 8; kt++) {
        lacc = MFMA16K16(ones, pfrag[kt], lacc, 0, 0, 0);
#pragma unroll
        for (int md = 0; md < 4; md++) {
          const int d = md * 16 + l16;
          const int pos = (kt * 2 + (quad >> 1)) ^ (d & 15);
          bf16x4 va =
              *(const bf16x4*)(Vts + d * 128 + pos * 8 + (quad & 1) * 4);
          oacc[md] = MFMA16K16(va, pfrag[kt], oacc[md], 0, 0, 0);
        }
      }
    }

    // ---- epilogue: every lane holds its q's full denominator ----
    const float inv = 1.0f / lacc[0];
    const int srow = q0 + w * 16 + l16;
#pragma unroll
    for (int md = 0; md < 4; md++) {
      bf16x4 o4;
#pragma unroll
      for (int r = 0; r < 4; r++) o4[r] = f2bf(oacc[md][r] * inv);
      *(bf16x4*)(attn + ((size_t)b * 2048 + srow) * 1024 + h * 64 + md * 16 +
                 quad * 4) = o4;
    }
  }
}

// ---------------------------------------------------------------------------
// Kernel 3: out = attn @ Wout^T (fp32 output). 128x64 tiles, grid (32,16)
// = 512 blocks = 2/CU. TRANSPOSED product -> float4 stores (1 KB/inst).
// ---------------------------------------------------------------------------
__global__ __launch_bounds__(256) void out_gemm(
    const bf16* __restrict__ attn, const bf16* __restrict__ Wout,
    float* __restrict__ out) {
  __shared__ bf16 As[128 * 32];
  __shared__ bf16 Bs[64 * 32];
  f32x4 acc[4][2];
#pragma unroll
  for (int i = 0; i < 4; i++)
#pragma unroll
    for (int j = 0; j < 2; j++) acc[i][j] = (f32x4){0.f, 0.f, 0.f, 0.f};
  const int bm = blockIdx.x, bn = blockIdx.y;
  const int t = threadIdx.x, w = t >> 6, l = t & 63;
  const int quad = l >> 4, l16 = l & 15;
  const int wm = (w >> 1) * 64, wn = (w & 1) * 32;
  const int c0 = t, c1 = t + 256;
  const bf16* a0 = attn + (size_t)(bm * 128 + (c0 >> 2)) * 1024 + (c0 & 3) * 8;
  const bf16* a1 = attn + (size_t)(bm * 128 + (c1 >> 2)) * 1024 + (c1 & 3) * 8;
  const bf16* b0 = Wout + (size_t)(bn * 64 + (t >> 2)) * 1024 + (t & 3) * 8;
  for (int k0 = 0; k0 < 1024; k0 += 32) {
    __syncthreads();
    gl_lds16(a0 + k0, As + c0 * 8);
    gl_lds16(a1 + k0, As + c1 * 8);
    gl_lds16(b0 + k0, Bs + t * 8);
    __syncthreads();
    bf16x8 af[4], bg[2];
#pragma unroll
    for (int i = 0; i < 4; i++)
      af[i] = *(const bf16x8*)(As + (wm + i * 16 + l16) * 32 + quad * 8);
#pragma unroll
    for (int j = 0; j < 2; j++)
      bg[j] = *(const bf16x8*)(Bs + (wn + j * 16 + l16) * 32 + quad * 8);
#pragma unroll
    for (int i = 0; i < 4; i++)
#pragma unroll
      for (int j = 0; j < 2; j++)
        acc[i][j] = MFMA16(bg[j], af[i], acc[i][j], 0, 0, 0);  // transposed
  }
  // transposed epilogue: m on l16, n on quad*4+r (4 contiguous n -> float4)
#pragma unroll
  for (int i = 0; i < 4; i++) {
    const int m = bm * 128 + wm + i * 16 + l16;
#pragma unroll
    for (int j = 0; j < 2; j++) {
      const int n0 = bn * 64 + wn + j * 16 + quad * 4;
      float4 st = {acc[i][j][0], acc[i][j][1], acc[i][j][2], acc[i][j][3]};
      *(float4*)(out + (size_t)m * 1024 + n0) = st;
    }
  }
}

// ---------------------------------------------------------------------------
extern "C" void kernel_launch(void* const* d_in, const int* in_sizes, int n_in,
                              void* d_out, int out_size, void* d_ws, size_t ws_size,
                              hipStream_t stream) {
  const float* x = (const float*)d_in[0];      // [2,2048,1024] fp32
  const float* Wqkv = (const float*)d_in[1];   // [3072,1024]   fp32
  const float* Wout = (const float*)d_in[2];   // [1024,1024]   fp32
  float* out = (float*)d_out;                  // [2,2048,1024] fp32

  char* ws = (char*)d_ws;
  const size_t MB = 1024 * 1024;
  bf16* xb = (bf16*)(ws + 0 * MB);      // [4096][1024]  8 MB (consumed by qkv)
  bf16* at = (bf16*)(ws + 0 * MB);      // [4096][1024]  8 MB (alias, after qkv)
  bf16* Wqkvb = (bf16*)(ws + 8 * MB);   // [3072][1024]  6 MB
  bf16* Woutb = (bf16*)(ws + 14 * MB);  // [1024][1024]  2 MB
  bf16* Qb = (bf16*)(ws + 16 * MB);     // [32][2048][64] 8 MB (pre-scaled)
  bf16* Kb = (bf16*)(ws + 24 * MB);     // [32][2048][64] 8 MB
  bf16* Vt = (bf16*)(ws + 32 * MB);     // [32][64][2048] 8 MB

  cvt_all<<<8192, 256, 0, stream>>>(x, Wqkv, Wout, xb, Wqkvb, Woutb);
  qkv_gemm<<<dim3(32, 24), 256, 0, stream>>>(xb, Wqkvb, Qb, Kb, Vt);
  attn_kernel<<<512, 256, 0, stream>>>(Qb, Kb, Vt, at);
  out_gemm<<<dim3(32, 16), 256, 0, stream>>>(at, Woutb, out);
}